// Round 1
// baseline (1446.651 us; speedup 1.0000x reference)
//
#include <hip/hip_runtime.h>
#include <hip/hip_bf16.h>
#include <stdint.h>

#define M_DIM 8192
#define N_DIM 11008
#define K_DIM 4096
#define KB_PACK (K_DIM / 2)   // 2048 packed int32 (one byte each) per W row

#define BM 128
#define BN 128
#define BK 32

typedef __bf16 bf16;
typedef __attribute__((ext_vector_type(8))) __bf16 bf16x8;
typedef __attribute__((ext_vector_type(4))) float f32x4;

// -------- async global->LDS (16B per lane; LDS dest = wave-uniform base + lane*16) --------
__device__ __forceinline__ void gload_lds16(const bf16* g, bf16* l) {
    __builtin_amdgcn_global_load_lds(
        (const __attribute__((address_space(1))) void*)g,
        (__attribute__((address_space(3))) void*)l,
        16, 0, 0);
}

// -------- pre-pass 1: x fp32 -> bf16, 8 elems/thread --------
__global__ void cvt_x_kernel(const float* __restrict__ x, bf16* __restrict__ xb) {
    size_t i = (size_t)blockIdx.x * blockDim.x + threadIdx.x;
    const float4* xv = (const float4*)x;
    float4 a = xv[2 * i];
    float4 b = xv[2 * i + 1];
    bf16x8 o;
    o[0] = (bf16)a.x; o[1] = (bf16)a.y; o[2] = (bf16)a.z; o[3] = (bf16)a.w;
    o[4] = (bf16)b.x; o[5] = (bf16)b.y; o[6] = (bf16)b.z; o[7] = (bf16)b.w;
    ((bf16x8*)xb)[i] = o;
}

// -------- pre-pass 2: unpack int4 (low nibble first) * scale -> bf16 W[N][K] --------
__global__ void dequant_w_kernel(const int* __restrict__ qw, const float* __restrict__ sc,
                                 bf16* __restrict__ wb) {
    size_t i = (size_t)blockIdx.x * blockDim.x + threadIdx.x;  // handles 4 packed int32
    int n = (int)(i >> 9);                                     // 512 threads per row (2048/4)
    float s = sc[n];
    int4 q = ((const int4*)qw)[i];
    bf16x8 o;
    int v, lo, hi;
    v = q.x & 255; lo = v & 15; lo -= (lo & 8) << 1; hi = (v >> 4) & 15; hi -= (hi & 8) << 1;
    o[0] = (bf16)(lo * s); o[1] = (bf16)(hi * s);
    v = q.y & 255; lo = v & 15; lo -= (lo & 8) << 1; hi = (v >> 4) & 15; hi -= (hi & 8) << 1;
    o[2] = (bf16)(lo * s); o[3] = (bf16)(hi * s);
    v = q.z & 255; lo = v & 15; lo -= (lo & 8) << 1; hi = (v >> 4) & 15; hi -= (hi & 8) << 1;
    o[4] = (bf16)(lo * s); o[5] = (bf16)(hi * s);
    v = q.w & 255; lo = v & 15; lo -= (lo & 8) << 1; hi = (v >> 4) & 15; hi -= (hi & 8) << 1;
    o[6] = (bf16)(lo * s); o[7] = (bf16)(hi * s);
    ((bf16x8*)wb)[i] = o;
}

// -------- main GEMM: C[m][n] = sum_k A[m][k] * B[n][k] + bias[n]  (B stored row-major [N][K]) --------
__global__ __launch_bounds__(256) void gemm_bt_kernel(
    const bf16* __restrict__ A,   // [M][K] bf16
    const bf16* __restrict__ B,   // [N][K] bf16 (dequantized W)
    const float* __restrict__ bias,
    float* __restrict__ C) {      // [M][N] fp32
    __shared__ bf16 As[BM * BK];
    __shared__ bf16 Bs[BN * BK];

    const int tid  = threadIdx.x;
    const int lane = tid & 63;
    const int wid  = tid >> 6;
    const int wm   = (wid >> 1) * 64;   // wave M offset in tile
    const int wn   = (wid & 1) * 64;    // wave N offset in tile
    const int m0   = blockIdx.y * BM;
    const int n0   = blockIdx.x * BN;

    // staging: thread t covers row r=t/4 (+64 for 2nd issue), 8 bf16 at col (t&3)*8
    // => for wave w lane i, LDS byte addr = wave-uniform base + i*16 (global_load_lds requirement)
    const int r  = tid >> 2;
    const int c8 = (tid & 3) * 8;
    const bf16* ga0 = A + (size_t)(m0 + r) * K_DIM + c8;
    const bf16* ga1 = A + (size_t)(m0 + r + 64) * K_DIM + c8;
    const bf16* gb0 = B + (size_t)(n0 + r) * K_DIM + c8;
    const bf16* gb1 = B + (size_t)(n0 + r + 64) * K_DIM + c8;
    bf16* la0 = As + r * BK + c8;
    bf16* la1 = As + (r + 64) * BK + c8;
    bf16* lb0 = Bs + r * BK + c8;
    bf16* lb1 = Bs + (r + 64) * BK + c8;

    const int l15 = lane & 15;
    const int kq  = (lane >> 4) * 8;    // k offset of this lane's 8-elem fragment

    f32x4 acc[4][4] = {};

    for (int k0 = 0; k0 < K_DIM; k0 += BK) {
        gload_lds16(ga0 + k0, la0);
        gload_lds16(ga1 + k0, la1);
        gload_lds16(gb0 + k0, lb0);
        gload_lds16(gb1 + k0, lb1);
        __syncthreads();   // compiler emits vmcnt(0) drain before barrier

        bf16x8 af[4], bfr[4];
#pragma unroll
        for (int i = 0; i < 4; ++i) {
            af[i]  = *(const bf16x8*)(As + (wm + i * 16 + l15) * BK + kq);
            bfr[i] = *(const bf16x8*)(Bs + (wn + i * 16 + l15) * BK + kq);
        }
#pragma unroll
        for (int mi = 0; mi < 4; ++mi)
#pragma unroll
            for (int ni = 0; ni < 4; ++ni)
                acc[mi][ni] = __builtin_amdgcn_mfma_f32_16x16x32_bf16(
                    af[mi], bfr[ni], acc[mi][ni], 0, 0, 0);
        __syncthreads();
    }

    // epilogue: C/D layout col = lane&15, row = (lane>>4)*4 + reg  [verified m89/m91]
    const int row0 = (lane >> 4) * 4;
#pragma unroll
    for (int ni = 0; ni < 4; ++ni) {
        int n = n0 + wn + ni * 16 + l15;
        float bv = bias[n];
#pragma unroll
        for (int mi = 0; mi < 4; ++mi) {
#pragma unroll
            for (int ri = 0; ri < 4; ++ri) {
                int m = m0 + wm + mi * 16 + row0 + ri;
                C[(size_t)m * N_DIM + n] = acc[mi][ni][ri] + bv;
            }
        }
    }
}

// -------- fallback (only if workspace too small): naive fused dequant dot --------
__global__ void fallback_kernel(const float* __restrict__ x, const int* __restrict__ qw,
                                const float* __restrict__ sc, const float* __restrict__ bias,
                                float* __restrict__ y) {
    int m = blockIdx.y;
    int n = blockIdx.x * 256 + threadIdx.x;
    __shared__ float xs[K_DIM];
    for (int k = threadIdx.x; k < K_DIM; k += 256) xs[k] = x[(size_t)m * K_DIM + k];
    __syncthreads();
    if (n < N_DIM) {
        float acc = 0.f;
        const int* qr = qw + (size_t)n * KB_PACK;
        for (int kb = 0; kb < KB_PACK; ++kb) {
            int v = qr[kb] & 255;
            int lo = v & 15; lo -= (lo & 8) << 1;
            int hi = (v >> 4) & 15; hi -= (hi & 8) << 1;
            acc += xs[2 * kb] * (float)lo + xs[2 * kb + 1] * (float)hi;
        }
        y[(size_t)m * N_DIM + n] = acc * sc[n] + bias[n];
    }
}

extern "C" void kernel_launch(void* const* d_in, const int* in_sizes, int n_in,
                              void* d_out, int out_size, void* d_ws, size_t ws_size,
                              hipStream_t stream) {
    const float* x    = (const float*)d_in[0];
    const int*   qw   = (const int*)d_in[1];
    const float* sc   = (const float*)d_in[2];
    const float* bias = (const float*)d_in[3];
    float*       y    = (float*)d_out;

    const size_t xb_elems = (size_t)M_DIM * K_DIM;
    const size_t wb_elems = (size_t)N_DIM * K_DIM;
    const size_t need = (xb_elems + wb_elems) * sizeof(bf16);

    if (ws_size >= need) {
        bf16* xb = (bf16*)d_ws;
        bf16* wb = xb + xb_elems;
        cvt_x_kernel<<<(int)(xb_elems / 8 / 256), 256, 0, stream>>>(x, xb);
        dequant_w_kernel<<<(int)((size_t)N_DIM * KB_PACK / 4 / 256), 256, 0, stream>>>(qw, sc, wb);
        gemm_bt_kernel<<<dim3(N_DIM / BN, M_DIM / BM), 256, 0, stream>>>(xb, wb, bias, y);
    } else {
        fallback_kernel<<<dim3((N_DIM + 255) / 256, M_DIM), 256, 0, stream>>>(x, qw, sc, bias, y);
    }
}

// Round 2
// 1042.592 us; speedup vs baseline: 1.3876x; 1.3876x over previous
//
#include <hip/hip_runtime.h>
#include <stdint.h>

#define M_DIM 8192
#define N_DIM 11008
#define K_DIM 4096
#define KB_PACK 2048          // packed int32 (one byte each) per W row

#define BM 128
#define BN 128
#define BK 64                 // 64 i8 per row per k-step = 64 B rows

typedef __attribute__((ext_vector_type(4))) int   i32x4;
typedef __attribute__((ext_vector_type(4))) float f32x4;

// -------- async global->LDS (16B per lane; LDS dest = wave-uniform base + lane*16) --------
__device__ __forceinline__ void gload_lds16(const int8_t* g, int8_t* l) {
    __builtin_amdgcn_global_load_lds(
        (const __attribute__((address_space(1))) void*)g,
        (__attribute__((address_space(3))) void*)l,
        16, 0, 0);
}

// -------- pre-pass 1: per-row absmax int8 quantization of x --------
// grid = M_DIM blocks x 256 threads; each thread handles 16 floats.
__global__ __launch_bounds__(256) void quant_x_kernel(const float* __restrict__ x,
                                                      int8_t* __restrict__ xq,
                                                      float* __restrict__ xs) {
    const int m   = blockIdx.x;
    const int tid = threadIdx.x;
    const float4* row = (const float4*)(x + (size_t)m * K_DIM);

    float4 v[4];
    float amax = 0.f;
#pragma unroll
    for (int i = 0; i < 4; ++i) {
        v[i] = row[i * 256 + tid];                       // coalesced
        amax = fmaxf(amax, fmaxf(fmaxf(fabsf(v[i].x), fabsf(v[i].y)),
                                 fmaxf(fabsf(v[i].z), fabsf(v[i].w))));
    }
    // wave reduce (64 lanes) then cross-wave via LDS
#pragma unroll
    for (int off = 32; off > 0; off >>= 1)
        amax = fmaxf(amax, __shfl_xor(amax, off));
    __shared__ float red[4];
    if ((tid & 63) == 0) red[tid >> 6] = amax;
    __syncthreads();
    amax = fmaxf(fmaxf(red[0], red[1]), fmaxf(red[2], red[3]));

    const float safe = fmaxf(amax, 1e-20f);
    const float inv  = 127.f / safe;
    if (tid == 0) xs[m] = safe * (1.f / 127.f);

    int* out = (int*)(xq + (size_t)m * K_DIM);
#pragma unroll
    for (int i = 0; i < 4; ++i) {
        int c0 = __float2int_rn(v[i].x * inv);
        int c1 = __float2int_rn(v[i].y * inv);
        int c2 = __float2int_rn(v[i].z * inv);
        int c3 = __float2int_rn(v[i].w * inv);
        out[i * 256 + tid] = (c0 & 255) | ((c1 & 255) << 8) | ((c2 & 255) << 16) | (c3 << 24);
    }
}

// -------- pre-pass 2: unpack int4 (low nibble first) -> int8, NO scale (folded into epilogue) --------
__device__ __forceinline__ int unpack2(int v0, int v1) {
    int l0 = (((v0 & 15) ^ 8) - 8) & 255;
    int h0 = ((((v0 >> 4) & 15) ^ 8) - 8) & 255;
    int l1 = (((v1 & 15) ^ 8) - 8) & 255;
    int h1 = ((((v1 >> 4) & 15) ^ 8) - 8) & 255;
    return l0 | (h0 << 8) | (l1 << 16) | (h1 << 24);
}

__global__ __launch_bounds__(256) void unpack_w_kernel(const int* __restrict__ qw,
                                                       int8_t* __restrict__ wq) {
    size_t i = (size_t)blockIdx.x * 256 + threadIdx.x;   // 8 packed int32 -> 16 i8
    const i32x4* q4 = (const i32x4*)qw;
    i32x4 a = q4[2 * i];
    i32x4 b = q4[2 * i + 1];
    i32x4 o;
    o.x = unpack2(a.x, a.y);
    o.y = unpack2(a.z, a.w);
    o.z = unpack2(b.x, b.y);
    o.w = unpack2(b.z, b.w);
    ((i32x4*)wq)[i] = o;
}

// -------- main GEMM: acc[m][n] = sum_k xq[m][k]*wq[n][k] (exact i32); epilogue applies scales+bias --------
__global__ __launch_bounds__(256) void gemm_i8_kernel(
    const int8_t* __restrict__ A,   // [M][K] i8
    const int8_t* __restrict__ B,   // [N][K] i8
    const float* __restrict__ xs,   // [M] x scales
    const float* __restrict__ wsc,  // [N] w scales
    const float* __restrict__ bias, // [N]
    float* __restrict__ C) {        // [M][N] fp32
    __shared__ int8_t As[BM * BK];  // 8 KB
    __shared__ int8_t Bs[BN * BK];  // 8 KB

    const int tid  = threadIdx.x;
    const int lane = tid & 63;
    const int wid  = tid >> 6;
    const int wm   = (wid >> 1) * 64;
    const int wn   = (wid & 1) * 64;
    const int m0   = blockIdx.y * BM;
    const int n0   = blockIdx.x * BN;

    // staging: thread t -> row r=t>>2 (+64 on 2nd issue), 16B at byte col (t&3)*16
    // LDS addr = t*16 => wave-uniform base + lane*16  (global_load_lds contract)
    const int r   = tid >> 2;
    const int c16 = (tid & 3) * 16;
    const int8_t* ga0 = A + (size_t)(m0 + r) * K_DIM + c16;
    const int8_t* ga1 = A + (size_t)(m0 + r + 64) * K_DIM + c16;
    const int8_t* gb0 = B + (size_t)(n0 + r) * K_DIM + c16;
    const int8_t* gb1 = B + (size_t)(n0 + r + 64) * K_DIM + c16;
    int8_t* la0 = As + r * BK + c16;
    int8_t* la1 = As + (r + 64) * BK + c16;
    int8_t* lb0 = Bs + r * BK + c16;
    int8_t* lb1 = Bs + (r + 64) * BK + c16;

    const int l15  = lane & 15;
    const int kq16 = (lane >> 4) * 16;   // byte offset of this lane's 16-elem k-fragment

    i32x4 acc[4][4] = {};

    for (int k0 = 0; k0 < K_DIM; k0 += BK) {
        gload_lds16(ga0 + k0, la0);
        gload_lds16(ga1 + k0, la1);
        gload_lds16(gb0 + k0, lb0);
        gload_lds16(gb1 + k0, lb1);
        __syncthreads();

        i32x4 af[4], bfr[4];
#pragma unroll
        for (int i = 0; i < 4; ++i) {
            af[i]  = *(const i32x4*)(As + (wm + i * 16 + l15) * BK + kq16);
            bfr[i] = *(const i32x4*)(Bs + (wn + i * 16 + l15) * BK + kq16);
        }
#pragma unroll
        for (int mi = 0; mi < 4; ++mi)
#pragma unroll
            for (int ni = 0; ni < 4; ++ni)
                acc[mi][ni] = __builtin_amdgcn_mfma_i32_16x16x64_i8(
                    af[mi], bfr[ni], acc[mi][ni], 0, 0, 0);
        __syncthreads();
    }

    // epilogue: C/D layout col = lane&15, row = (lane>>4)*4 + reg  (dtype-independent, m89/m121-128)
    const int row0 = (lane >> 4) * 4;
    float sm[4][4];
#pragma unroll
    for (int mi = 0; mi < 4; ++mi)
#pragma unroll
        for (int ri = 0; ri < 4; ++ri)
            sm[mi][ri] = xs[m0 + wm + mi * 16 + row0 + ri];

#pragma unroll
    for (int ni = 0; ni < 4; ++ni) {
        int n = n0 + wn + ni * 16 + l15;
        float sn = wsc[n];
        float bv = bias[n];
#pragma unroll
        for (int mi = 0; mi < 4; ++mi) {
#pragma unroll
            for (int ri = 0; ri < 4; ++ri) {
                int m = m0 + wm + mi * 16 + row0 + ri;
                C[(size_t)m * N_DIM + n] = (float)acc[mi][ni][ri] * (sm[mi][ri] * sn) + bv;
            }
        }
    }
}

// -------- fallback (only if workspace too small): naive fused dequant dot --------
__global__ void fallback_kernel(const float* __restrict__ x, const int* __restrict__ qw,
                                const float* __restrict__ sc, const float* __restrict__ bias,
                                float* __restrict__ y) {
    int m = blockIdx.y;
    int n = blockIdx.x * 256 + threadIdx.x;
    __shared__ float xsh[K_DIM];
    for (int k = threadIdx.x; k < K_DIM; k += 256) xsh[k] = x[(size_t)m * K_DIM + k];
    __syncthreads();
    if (n < N_DIM) {
        float acc = 0.f;
        const int* qr = qw + (size_t)n * KB_PACK;
        for (int kb = 0; kb < KB_PACK; ++kb) {
            int v = qr[kb] & 255;
            int lo = v & 15; lo -= (lo & 8) << 1;
            int hi = (v >> 4) & 15; hi -= (hi & 8) << 1;
            acc += xsh[2 * kb] * (float)lo + xsh[2 * kb + 1] * (float)hi;
        }
        y[(size_t)m * N_DIM + n] = acc * sc[n] + bias[n];
    }
}

extern "C" void kernel_launch(void* const* d_in, const int* in_sizes, int n_in,
                              void* d_out, int out_size, void* d_ws, size_t ws_size,
                              hipStream_t stream) {
    const float* x    = (const float*)d_in[0];
    const int*   qw   = (const int*)d_in[1];
    const float* sc   = (const float*)d_in[2];
    const float* bias = (const float*)d_in[3];
    float*       y    = (float*)d_out;

    const size_t xq_bytes = (size_t)M_DIM * K_DIM;            // 33.5 MB i8
    const size_t wq_bytes = (size_t)N_DIM * K_DIM;            // 45 MB i8
    const size_t xs_bytes = (size_t)M_DIM * sizeof(float);    // 32 KB
    const size_t need = xq_bytes + wq_bytes + xs_bytes;

    if (ws_size >= need) {
        int8_t* xq = (int8_t*)d_ws;
        int8_t* wq = xq + xq_bytes;
        float*  xs = (float*)(wq + wq_bytes);
        quant_x_kernel<<<M_DIM, 256, 0, stream>>>(x, xq, xs);
        unpack_w_kernel<<<(int)((size_t)N_DIM * K_DIM / 16 / 256), 256, 0, stream>>>(qw, wq);
        gemm_i8_kernel<<<dim3(N_DIM / BN, M_DIM / BM), 256, 0, stream>>>(xq, wq, xs, sc, bias, y);
    } else {
        fallback_kernel<<<dim3((N_DIM + 255) / 256, M_DIM), 256, 0, stream>>>(x, qw, sc, bias, y);
    }
}